// Round 2
// baseline (83.998 us; speedup 1.0000x reference)
//
#include <hip/hip_runtime.h>
#include <hip/hip_bf16.h>

// LDPC normalized min-sum decoder, B=8, M=1024 checks, N=2048 vars, deg<=~10.
// Round 1 -> 2 restructure: cv messages live entirely in registers (one check
// row per thread); column sums are formed by LDS atomicAdd scatter, killing
// the CSC structures, the cv LDS array, and all in-loop global traffic.

#define M_CHECK 1024
#define N_VAR   2048
#define BATCH   8
#define MAXD    12
#define NUM_ITERS 5

// ---------------------------------------------------------------------------
// Kernel A: wave-per-row ordered compaction of dense H -> deg, row_cols
// (column-major [MAXD][M] for coalesced decode loads). int4-vectorized:
// 8 x 16B loads per lane per row. Deterministic ballot/popcount ranking.
__global__ __launch_bounds__(256) void build_rows_kernel(
    const int* __restrict__ H, int* __restrict__ deg,
    int* __restrict__ row_cols_T)
{
    const int m    = blockIdx.x * 4 + (threadIdx.x >> 6);   // wave per row
    const int lane = threadIdx.x & 63;
    const unsigned long long below = (1ULL << lane) - 1ULL;
    const int4* __restrict__ H4 = (const int4*)(H + m * N_VAR);

    int base = 0;
    for (int c = 0; c < N_VAR; c += 256) {                  // 256 cols per pass
        int4 h = H4[(c >> 2) + lane];                       // cols c+4*lane+{0..3}
        unsigned long long m0 = __ballot(h.x != 0);
        unsigned long long m1 = __ballot(h.y != 0);
        unsigned long long m2 = __ballot(h.z != 0);
        unsigned long long m3 = __ballot(h.w != 0);
        int pb = __popcll(m0 & below) + __popcll(m1 & below)
               + __popcll(m2 & below) + __popcll(m3 & below);
        int b0 = (int)((m0 >> lane) & 1);
        int b1 = (int)((m1 >> lane) & 1);
        int b2 = (int)((m2 >> lane) & 1);
        int col = c + 4 * lane;
        int r = base + pb;
        if (h.x) { if (r < MAXD) row_cols_T[r * M_CHECK + m] = col; }
        r += b0;
        if (h.y) { if (r < MAXD) row_cols_T[r * M_CHECK + m] = col + 1; }
        r += b1;
        if (h.z) { if (r < MAXD) row_cols_T[r * M_CHECK + m] = col + 2; }
        r += b2;
        if (h.w) { if (r < MAXD) row_cols_T[r * M_CHECK + m] = col + 3; }
        base += __popcll(m0) + __popcll(m1) + __popcll(m2) + __popcll(m3);
    }
    if (lane == 0) deg[m] = (base < MAXD) ? base : MAXD;
}

// ---------------------------------------------------------------------------
// Kernel B: full decode. One block per batch; thread t owns check row t and
// variable columns t, t+1024. cv in registers; colsum in 8KB LDS.
__global__ __launch_bounds__(1024) void decode_kernel(
    const float* __restrict__ soft_input, const float* __restrict__ check_weight,
    const int* __restrict__ deg, const int* __restrict__ row_cols_T,
    float* __restrict__ out)
{
    __shared__ float colsum[N_VAR];

    const int b = blockIdx.x;
    const int t = threadIdx.x;
    const float alpha = log1pf(expf(check_weight[0]));      // softplus(w)

    const int n0 = t, n1 = t + 1024;
    const float soft0 = soft_input[b * N_VAR + n0];
    const float soft1 = soft_input[b * N_VAR + n1];

    const int dm = deg[t];
    int   cols[MAXD];
    float cv[MAXD];
#pragma unroll
    for (int d = 0; d < MAXD; ++d) {
        cols[d] = (d < dm) ? row_cols_T[d * M_CHECK + t] : 0;   // coalesced
        cv[d]   = 0.f;
    }

    colsum[n0] = soft0;
    colsum[n1] = soft1;
    __syncthreads();

    for (int it = 0; it < NUM_ITERS; ++it) {
        // --- scatter: colsum[n] = soft[n] + sum of column-n messages
#pragma unroll
        for (int d = 0; d < MAXD; ++d)
            if (d < dm) atomicAdd(&colsum[cols[d]], cv[d]);
        __syncthreads();

        // --- gather this row's column totals into registers
        float vcsum[MAXD];
#pragma unroll
        for (int d = 0; d < MAXD; ++d)
            vcsum[d] = (d < dm) ? colsum[cols[d]] : 0.f;
        __syncthreads();

        // --- re-init colsum for next iteration (overlaps with reg compute)
        colsum[n0] = soft0;
        colsum[n1] = soft1;

        // --- check update: exclude-self min/submin + sign product (all regs)
        float mn1 = 1e38f, mn2 = 1e38f, sprod = 1.f;
        float vcs[MAXD];
#pragma unroll
        for (int d = 0; d < MAXD; ++d) {
            if (d < dm) {
                float vc = vcsum[d] - cv[d];                 // exclude own msg
                vcs[d] = vc;
                float a = fminf(fabsf(vc), 1e30f);
                if (a < mn1) { mn2 = mn1; mn1 = a; }
                else if (a < mn2) { mn2 = a; }
                sprod *= (vc > 0.f) ? 1.f : ((vc < 0.f) ? -1.f : 0.f);
            }
        }
#pragma unroll
        for (int d = 0; d < MAXD; ++d) {
            if (d < dm) {
                float vc  = vcs[d];
                float a   = fminf(fabsf(vc), 1e30f);
                float res = (a > mn1) ? mn1 : mn2;           // exclude-self min
                float sg  = (vc > 0.f) ? 1.f : ((vc < 0.f) ? -1.f : 0.f);
                cv[d] = res * (sprod * sg) * alpha;
            }
        }
        __syncthreads();
    }

    // --- final posterior: one more scatter, then write both columns
#pragma unroll
    for (int d = 0; d < MAXD; ++d)
        if (d < dm) atomicAdd(&colsum[cols[d]], cv[d]);
    __syncthreads();

    out[b * N_VAR + n0] = colsum[n0];
    out[b * N_VAR + n1] = colsum[n1];
}

// ---------------------------------------------------------------------------
extern "C" void kernel_launch(void* const* d_in, const int* in_sizes, int n_in,
                              void* d_out, int out_size, void* d_ws, size_t ws_size,
                              hipStream_t stream)
{
    const float* soft_input   = (const float*)d_in[0];
    const float* check_weight = (const float*)d_in[1];
    const int*   H            = (const int*)d_in[2];
    float*       out          = (float*)d_out;

    int* deg        = (int*)d_ws;                  // M
    int* row_cols_T = deg + M_CHECK;               // MAXD * M (col-major)

    build_rows_kernel<<<M_CHECK / 4, 256, 0, stream>>>(H, deg, row_cols_T);
    decode_kernel<<<BATCH, 1024, 0, stream>>>(
        soft_input, check_weight, deg, row_cols_T, out);
}

// Round 3
// 50.260 us; speedup vs baseline: 1.6713x; 1.6713x over previous
//
#include <hip/hip_runtime.h>
#include <hip/hip_bf16.h>

// LDPC normalized min-sum decoder, B=8, M=1024 checks, N=2048 vars, deg<=~11.
// Round 2 -> 3: kill the LDS float-atomicAdd CAS loops (75us of latency).
// Decode loop is now pure ds_read/ds_write + registers:
//   row phase:    gather colsum, min/submin + sign (XOR bits), write cv to LDS
//   column phase: gather cv via register-held sorted CSC lists, write colsum
// CSC built once per launch (deterministic via post-sort), decode loads it
// into registers with static unrolled indices (no scratch spill).

#define M_CHECK 1024
#define N_VAR   2048
#define BATCH   8
#define MAXD    12              // max check-row degree (actual <= ~11)
#define CMAX    16              // max variable-col degree (Poisson(4), max ~14)
#define CV_STRIDE 13            // 13 coprime 32 banks -> conflict-free row writes
#define NUM_ITERS 5

// ---------------------------------------------------------------------------
// Kernel A: wave-per-row ordered compaction of dense H -> deg, row_cols_T
// (column-major [MAXD][M] for coalesced decode loads). Also zeros col_cnt.
__global__ __launch_bounds__(256) void build_rows_kernel(
    const int* __restrict__ H, int* __restrict__ deg,
    int* __restrict__ row_cols_T, int* __restrict__ col_cnt)
{
    int gtid = blockIdx.x * 256 + threadIdx.x;
    if (gtid < N_VAR) col_cnt[gtid] = 0;

    const int m    = blockIdx.x * 4 + (threadIdx.x >> 6);   // wave per row
    const int lane = threadIdx.x & 63;
    const unsigned long long below = (1ULL << lane) - 1ULL;
    const int4* __restrict__ H4 = (const int4*)(H + m * N_VAR);

    int base = 0;
    for (int c = 0; c < N_VAR; c += 256) {                  // 256 cols per pass
        int4 h = H4[(c >> 2) + lane];
        unsigned long long m0 = __ballot(h.x != 0);
        unsigned long long m1 = __ballot(h.y != 0);
        unsigned long long m2 = __ballot(h.z != 0);
        unsigned long long m3 = __ballot(h.w != 0);
        int pb = __popcll(m0 & below) + __popcll(m1 & below)
               + __popcll(m2 & below) + __popcll(m3 & below);
        int b0 = (int)((m0 >> lane) & 1);
        int b1 = (int)((m1 >> lane) & 1);
        int b2 = (int)((m2 >> lane) & 1);
        int col = c + 4 * lane;
        int r = base + pb;
        if (h.x) { if (r < MAXD) row_cols_T[r * M_CHECK + m] = col; }
        r += b0;
        if (h.y) { if (r < MAXD) row_cols_T[r * M_CHECK + m] = col + 1; }
        r += b1;
        if (h.z) { if (r < MAXD) row_cols_T[r * M_CHECK + m] = col + 2; }
        r += b2;
        if (h.w) { if (r < MAXD) row_cols_T[r * M_CHECK + m] = col + 3; }
        base += __popcll(m0) + __popcll(m1) + __popcll(m2) + __popcll(m3);
    }
    if (lane == 0) deg[m] = (base < MAXD) ? base : MAXD;
}

// ---------------------------------------------------------------------------
// Kernel B: scatter edges into column lists (atomic append; order fixed by C).
// Edge id = m*CV_STRIDE + d  (matches decode's LDS cv layout).
__global__ __launch_bounds__(256) void build_cols_kernel(
    const int* __restrict__ deg, const int* __restrict__ row_cols_T,
    int* __restrict__ col_cnt, int* __restrict__ col_edge)
{
    int m = blockIdx.x * 256 + threadIdx.x;
    if (m >= M_CHECK) return;
    int dm = deg[m];
    for (int d = 0; d < dm; ++d) {
        int col = row_cols_T[d * M_CHECK + m];
        int pos = atomicAdd(&col_cnt[col], 1);
        if (pos < CMAX) col_edge[col * CMAX + pos] = m * CV_STRIDE + d;
    }
}

// ---------------------------------------------------------------------------
// Kernel C: per-column insertion sort -> deterministic gather order.
// (Data-dependent indexing spills to scratch here; harmless off the hot path.)
__global__ __launch_bounds__(256) void sort_cols_kernel(
    int* __restrict__ col_cnt, int* __restrict__ col_edge)
{
    int n = blockIdx.x * 256 + threadIdx.x;
    if (n >= N_VAR) return;
    int cnt = min(col_cnt[n], CMAX);
    col_cnt[n] = cnt;
    int e[CMAX];
    for (int k = 0; k < cnt; ++k) e[k] = col_edge[n * CMAX + k];
    for (int i = 1; i < cnt; ++i) {
        int v = e[i]; int j = i - 1;
        while (j >= 0 && e[j] > v) { e[j + 1] = e[j]; --j; }
        e[j + 1] = v;
    }
    for (int k = 0; k < cnt; ++k) col_edge[n * CMAX + k] = e[k];
}

// ---------------------------------------------------------------------------
// Kernel D: full decode. One block per batch; thread t owns check row t and
// variable columns t, t+1024. cv in LDS (written only by its owning row
// thread), colsum in LDS. No atomics, no global memory in the loop.
__global__ __launch_bounds__(1024) void decode_kernel(
    const float* __restrict__ soft_input, const float* __restrict__ check_weight,
    const int* __restrict__ deg, const int* __restrict__ row_cols_T,
    const int* __restrict__ col_cnt, const int* __restrict__ col_edge,
    float* __restrict__ out)
{
    __shared__ float cv_s[M_CHECK * CV_STRIDE];   // 52 KB
    __shared__ float colsum[N_VAR];               //  8 KB

    const int b = blockIdx.x;
    const int t = threadIdx.x;
    const float alpha = log1pf(expf(check_weight[0]));   // softplus(w)

    // ---- column-owner state (2 columns per thread), all in registers
    const int n0 = t, n1 = t + 1024;
    const float soft0 = soft_input[b * N_VAR + n0];
    const float soft1 = soft_input[b * N_VAR + n1];
    const int c0 = min(col_cnt[n0], CMAX);
    const int c1 = min(col_cnt[n1], CMAX);
    int eid0[CMAX], eid1[CMAX];
#pragma unroll
    for (int k = 0; k < CMAX; ++k) {
        eid0[k] = (k < c0) ? col_edge[n0 * CMAX + k] : 0;
        eid1[k] = (k < c1) ? col_edge[n1 * CMAX + k] : 0;
    }

    // ---- row-owner state
    const int dm = deg[t];
    int   cols[MAXD];
    float cv[MAXD];
#pragma unroll
    for (int d = 0; d < MAXD; ++d) {
        cols[d] = (d < dm) ? row_cols_T[d * M_CHECK + t] : 0;   // coalesced
        cv[d]   = 0.f;
    }

    colsum[n0] = soft0;
    colsum[n1] = soft1;
    float s0 = soft0, s1 = soft1;
    __syncthreads();

    for (int it = 0; it < NUM_ITERS; ++it) {
        // --- row phase: vc = colsum - own cv; min/submin; sign product
        float mn1 = 1e38f, mn2 = 1e38f;
        unsigned sx = 0u;            // XOR of sign bits over the row's edges
        bool zr = false;             // any exact-zero vc -> whole row zeroes
        float vcs[MAXD];
#pragma unroll
        for (int d = 0; d < MAXD; ++d) {
            if (d < dm) {
                float vc = colsum[cols[d]] - cv[d];
                vcs[d] = vc;
                float a = fminf(fabsf(vc), 1e30f);
                if (a < mn1) { mn2 = mn1; mn1 = a; }
                else if (a < mn2) { mn2 = a; }
                sx ^= (__float_as_uint(vc) & 0x80000000u);
                zr |= (vc == 0.f);
            }
        }
        const float zmul = zr ? 0.f : alpha;
#pragma unroll
        for (int d = 0; d < MAXD; ++d) {
            if (d < dm) {
                float vc  = vcs[d];
                float a   = fminf(fabsf(vc), 1e30f);
                float res = (a > mn1) ? mn1 : mn2;            // exclude-self min
                unsigned others = sx ^ (__float_as_uint(vc) & 0x80000000u);
                float v = res * zmul;                          // >= 0
                cv[d] = __uint_as_float(__float_as_uint(v) ^ others);
                cv_s[t * CV_STRIDE + d] = cv[d];               // bank-free write
            }
        }
        __syncthreads();

        // --- column phase: colsum[n] = soft[n] + sum of column-n messages
        s0 = soft0;
#pragma unroll
        for (int k = 0; k < CMAX; ++k)
            if (k < c0) s0 += cv_s[eid0[k]];
        colsum[n0] = s0;
        s1 = soft1;
#pragma unroll
        for (int k = 0; k < CMAX; ++k)
            if (k < c1) s1 += cv_s[eid1[k]];
        colsum[n1] = s1;
        __syncthreads();
    }

    // --- posterior LLRs (last column phase already computed them)
    out[b * N_VAR + n0] = s0;
    out[b * N_VAR + n1] = s1;
}

// ---------------------------------------------------------------------------
extern "C" void kernel_launch(void* const* d_in, const int* in_sizes, int n_in,
                              void* d_out, int out_size, void* d_ws, size_t ws_size,
                              hipStream_t stream)
{
    const float* soft_input   = (const float*)d_in[0];
    const float* check_weight = (const float*)d_in[1];
    const int*   H            = (const int*)d_in[2];
    float*       out          = (float*)d_out;

    int* deg        = (int*)d_ws;                       // M
    int* row_cols_T = deg + M_CHECK;                    // MAXD * M
    int* col_cnt    = row_cols_T + MAXD * M_CHECK;      // N
    int* col_edge   = col_cnt + N_VAR;                  // N * CMAX

    build_rows_kernel<<<M_CHECK / 4, 256, 0, stream>>>(H, deg, row_cols_T, col_cnt);
    build_cols_kernel<<<M_CHECK / 256, 256, 0, stream>>>(
        deg, row_cols_T, col_cnt, col_edge);
    sort_cols_kernel<<<N_VAR / 256, 256, 0, stream>>>(col_cnt, col_edge);
    decode_kernel<<<BATCH, 1024, 0, stream>>>(
        soft_input, check_weight, deg, row_cols_T, col_cnt, col_edge, out);
}

// Round 4
// 20.870 us; speedup vs baseline: 4.0247x; 2.4082x over previous
//
#include <hip/hip_runtime.h>
#include <hip/hip_bf16.h>

// LDPC normalized min-sum decoder, B=8, M=1024 checks, N=2048 vars, deg<=~11.
// Round 3 -> 4: delete the CSC build (build_cols + scratch-bound sort_cols)
// entirely. Column sums are accumulated with native ds_add_u32 integer
// atomics in Q14 fixed point (commutative -> bitwise deterministic; no CAS
// loop, unlike float atomicAdd). Three rotating accumulators give one
// barrier per decode iteration:
//   iter i: gather acc[i%3], scatter acc[(i+1)%3], reset acc[(i+2)%3], barrier
// Two kernel launches total.

#define M_CHECK 1024
#define N_VAR   2048
#define BATCH   8
#define MAXD    12               // max check-row degree (actual <= ~11)
#define NUM_ITERS 5
#define FXS 16384.0f             // Q14 fixed-point scale
#define FXI (1.0f / 16384.0f)

// ---------------------------------------------------------------------------
// Kernel A: wave-per-row ordered compaction of dense H -> deg, row_cols_T
// (column-major [MAXD][M] for coalesced decode loads). int4-vectorized,
// deterministic ballot/popcount ranking.
__global__ __launch_bounds__(256) void build_rows_kernel(
    const int* __restrict__ H, int* __restrict__ deg,
    int* __restrict__ row_cols_T)
{
    const int m    = blockIdx.x * 4 + (threadIdx.x >> 6);   // wave per row
    const int lane = threadIdx.x & 63;
    const unsigned long long below = (1ULL << lane) - 1ULL;
    const int4* __restrict__ H4 = (const int4*)(H + m * N_VAR);

    int base = 0;
    for (int c = 0; c < N_VAR; c += 256) {                  // 256 cols per pass
        int4 h = H4[(c >> 2) + lane];
        unsigned long long m0 = __ballot(h.x != 0);
        unsigned long long m1 = __ballot(h.y != 0);
        unsigned long long m2 = __ballot(h.z != 0);
        unsigned long long m3 = __ballot(h.w != 0);
        int pb = __popcll(m0 & below) + __popcll(m1 & below)
               + __popcll(m2 & below) + __popcll(m3 & below);
        int b0 = (int)((m0 >> lane) & 1);
        int b1 = (int)((m1 >> lane) & 1);
        int b2 = (int)((m2 >> lane) & 1);
        int col = c + 4 * lane;
        int r = base + pb;
        if (h.x) { if (r < MAXD) row_cols_T[r * M_CHECK + m] = col; }
        r += b0;
        if (h.y) { if (r < MAXD) row_cols_T[r * M_CHECK + m] = col + 1; }
        r += b1;
        if (h.z) { if (r < MAXD) row_cols_T[r * M_CHECK + m] = col + 2; }
        r += b2;
        if (h.w) { if (r < MAXD) row_cols_T[r * M_CHECK + m] = col + 3; }
        base += __popcll(m0) + __popcll(m1) + __popcll(m2) + __popcll(m3);
    }
    if (lane == 0) deg[m] = (base < MAXD) ? base : MAXD;
}

// ---------------------------------------------------------------------------
// Kernel B: full decode. One block per batch; thread t owns check row t and
// variable columns t, t+1024. cv in registers; column sums via Q14 integer
// LDS atomics into 3 rotating 8KB accumulators.
__global__ __launch_bounds__(1024) void decode_kernel(
    const float* __restrict__ soft_input, const float* __restrict__ check_weight,
    const int* __restrict__ deg, const int* __restrict__ row_cols_T,
    float* __restrict__ out)
{
    __shared__ int   acc[3][N_VAR];    // 24 KB fixed-point cv column sums
    __shared__ float soft_s[N_VAR];    //  8 KB

    const int b = blockIdx.x;
    const int t = threadIdx.x;
    const float alpha = log1pf(expf(check_weight[0]));   // softplus(w)

    const int n0 = t, n1 = t + 1024;
    const float soft0 = soft_input[b * N_VAR + n0];
    const float soft1 = soft_input[b * N_VAR + n1];
    soft_s[n0] = soft0;  soft_s[n1] = soft1;
    acc[0][n0] = 0; acc[0][n1] = 0;
    acc[1][n0] = 0; acc[1][n1] = 0;
    acc[2][n0] = 0; acc[2][n1] = 0;

    const int dm = deg[t];
    int   cols[MAXD];
    float cv[MAXD];
#pragma unroll
    for (int d = 0; d < MAXD; ++d) {
        cols[d] = (d < dm) ? row_cols_T[d * M_CHECK + t] : 0;   // coalesced
        cv[d]   = 0.f;
    }
    __syncthreads();

    // this row's per-edge soft inputs (registers; gathered from LDS once)
    float softc[MAXD];
#pragma unroll
    for (int d = 0; d < MAXD; ++d)
        softc[d] = (d < dm) ? soft_s[cols[d]] : 0.f;

#pragma unroll
    for (int it = 0; it < NUM_ITERS; ++it) {
        const int gb = it % 3;             // gather buffer (this iter's colsums)
        const int sb = (it + 1) % 3;       // scatter target (next iter's colsums)
        const int rb = (it + 2) % 3;       // reset (gathered last iter, zeroed now)

        float vcs[MAXD];
        float mn1 = 1e38f, mn2 = 1e38f;
        unsigned sx = 0u;                  // XOR of vc sign bits over the row
        bool zr = false;                   // any exact-zero vc -> row zeroes
#pragma unroll
        for (int d = 0; d < MAXD; ++d) {
            if (d < dm) {
                float colsum = softc[d] + (float)acc[gb][cols[d]] * FXI;
                float vc = colsum - cv[d];                 // exclude own message
                vcs[d] = vc;
                float a = fminf(fabsf(vc), 1e30f);
                if (a < mn1) { mn2 = mn1; mn1 = a; }
                else if (a < mn2) { mn2 = a; }
                sx ^= (__float_as_uint(vc) & 0x80000000u);
                zr |= (vc == 0.f);
            }
        }
        const float zmul = zr ? 0.f : alpha;
#pragma unroll
        for (int d = 0; d < MAXD; ++d) {
            if (d < dm) {
                float vc  = vcs[d];
                float a   = fminf(fabsf(vc), 1e30f);
                float res = (a > mn1) ? mn1 : mn2;         // exclude-self min
                unsigned others = sx ^ (__float_as_uint(vc) & 0x80000000u);
                float v = res * zmul;                      // >= 0
                float cvn = __uint_as_float(__float_as_uint(v) ^ others);
                cv[d] = cvn;
                atomicAdd(&acc[sb][cols[d]], __float2int_rn(cvn * FXS));
            }
        }
        acc[rb][n0] = 0;                   // safe: rb not gathered/scattered now
        acc[rb][n1] = 0;
        __syncthreads();
    }

    // posterior LLRs from the last scatter buffer
    const int fb = NUM_ITERS % 3;
    out[b * N_VAR + n0] = soft0 + (float)acc[fb][n0] * FXI;
    out[b * N_VAR + n1] = soft1 + (float)acc[fb][n1] * FXI;
}

// ---------------------------------------------------------------------------
extern "C" void kernel_launch(void* const* d_in, const int* in_sizes, int n_in,
                              void* d_out, int out_size, void* d_ws, size_t ws_size,
                              hipStream_t stream)
{
    const float* soft_input   = (const float*)d_in[0];
    const float* check_weight = (const float*)d_in[1];
    const int*   H            = (const int*)d_in[2];
    float*       out          = (float*)d_out;

    int* deg        = (int*)d_ws;                  // M
    int* row_cols_T = deg + M_CHECK;               // MAXD * M (col-major)

    build_rows_kernel<<<M_CHECK / 4, 256, 0, stream>>>(H, deg, row_cols_T);
    decode_kernel<<<BATCH, 1024, 0, stream>>>(
        soft_input, check_weight, deg, row_cols_T, out);
}